// Round 10
// baseline (236.969 us; speedup 1.0000x reference)
//
#include <hip/hip_runtime.h>
#include <math.h>

#define FI4(p) (*(const float4*)(p))

typedef _Float16 half8 __attribute__((ext_vector_type(8)));
typedef _Float16 half2v __attribute__((ext_vector_type(2)));
typedef float f32x4 __attribute__((ext_vector_type(4)));

__device__ __forceinline__ float gumbelf(float u) {
    return -__logf(-__logf(u + 1e-9f) + 1e-9f);
}

template<int CTRL>
__device__ __forceinline__ int dppmov(int v) {
    return __builtin_amdgcn_update_dpp(v, v, CTRL, 0xF, 0xF, false);
}
__device__ __forceinline__ float wave_max_bcast(float v) {
    v = fmaxf(v, __int_as_float(dppmov<0xB1>(__float_as_int(v))));
    v = fmaxf(v, __int_as_float(dppmov<0x4E>(__float_as_int(v))));
    v = fmaxf(v, __int_as_float(dppmov<0x141>(__float_as_int(v))));
    v = fmaxf(v, __int_as_float(dppmov<0x140>(__float_as_int(v))));
    v = fmaxf(v, __int_as_float(dppmov<0x142>(__float_as_int(v))));
    v = fmaxf(v, __int_as_float(dppmov<0x143>(__float_as_int(v))));
    return __int_as_float(__builtin_amdgcn_readlane(__float_as_int(v), 63));
}
__device__ __forceinline__ float wave_sum_bcast(float v) {
    v += __int_as_float(dppmov<0xB1>(__float_as_int(v)));
    v += __int_as_float(dppmov<0x4E>(__float_as_int(v)));
    v += __int_as_float(dppmov<0x141>(__float_as_int(v)));
    v += __int_as_float(dppmov<0x140>(__float_as_int(v)));
    v += __int_as_float(dppmov<0x142>(__float_as_int(v)));
    v += __int_as_float(dppmov<0x143>(__float_as_int(v)));
    return __int_as_float(__builtin_amdgcn_readlane(__float_as_int(v), 63));
}

__device__ __forceinline__ unsigned ordkey(float f) {
    unsigned x = __float_as_uint(f);
    return x ^ ((unsigned)((int)x >> 31) | 0x80000000u);
}

__device__ __forceinline__ int mbcnt64(unsigned long long m) {
    return __builtin_amdgcn_mbcnt_hi((unsigned)(m >> 32),
           __builtin_amdgcn_mbcnt_lo((unsigned)m, 0));
}

__device__ __forceinline__ void copy8(unsigned long long* dst, const unsigned long long* src) {
    #pragma unroll
    for (int j = 0; j < 8; ++j) dst[j] = src[j];
}

// ties at key == hi filled by smallest n; n = (j>>2)*256 + lane*4 + (j&3)
__device__ __forceinline__ void tie_fill(const unsigned* u, unsigned long long* sel, unsigned hi)
{
    unsigned long long eq[8];
    int mcnt = 0;
    #pragma unroll
    for (int j = 0; j < 8; ++j) {
        sel[j] = __ballot(u[j] > hi);
        eq[j]  = __ballot(u[j] == hi);
        mcnt += __popcll(sel[j]);
    }
    int r = 16 - mcnt;
    #pragma unroll
    for (int jhi = 0; jhi < 2; ++jhi) {
        if (r > 0) {
            unsigned long long any = eq[jhi*4] | eq[jhi*4+1] | eq[jhi*4+2] | eq[jhi*4+3];
            while (any && r > 0) {
                int lane = (int)__builtin_ctzll(any); any &= any - 1;
                #pragma unroll
                for (int jlo = 0; jlo < 4; ++jlo) {
                    int j2 = jhi * 4 + jlo;
                    if (r > 0 && ((eq[j2] >> lane) & 1ull)) { sel[j2] |= 1ull << lane; --r; }
                }
            }
        }
    }
}

// Dual top-16 bisection: rows A and B searched in lockstep so the two
// dependent ballot->popcount->branch chains overlap (16 ballots in flight).
__device__ __forceinline__ void select16_pair(
    const unsigned* uA, const unsigned* uB,
    unsigned long long* selA, unsigned long long* selB,
    unsigned loA, unsigned hiA, unsigned loB, unsigned hiB)
{
    bool doneA = false, doneB = false;
    {
        unsigned long long mmA[8], mmB[8];
        int cA = 0, cB = 0;
        #pragma unroll
        for (int j = 0; j < 8; ++j) {
            mmA[j] = __ballot(uA[j] > loA); cA += __popcll(mmA[j]);
            mmB[j] = __ballot(uB[j] > loB); cB += __popcll(mmB[j]);
        }
        if (cA == 16) { copy8(selA, mmA); doneA = true; }
        else if (cA < 16) loA = 0u;   // ordkey(finite) > 0 => cnt(>0) = 512 > 16
        if (cB == 16) { copy8(selB, mmB); doneB = true; }
        else if (cB < 16) loB = 0u;
    }
    while ((!doneA && hiA - loA > 1u) || (!doneB && hiB - loB > 1u)) {
        bool pA = !doneA && (hiA - loA > 1u);
        bool pB = !doneB && (hiB - loB > 1u);
        unsigned midA = loA + ((hiA - loA) >> 1);
        unsigned midB = loB + ((hiB - loB) >> 1);
        unsigned long long mmA[8], mmB[8];
        int cA = 0, cB = 0;
        #pragma unroll
        for (int j = 0; j < 8; ++j) {
            mmA[j] = __ballot(uA[j] > midA); cA += __popcll(mmA[j]);
            mmB[j] = __ballot(uB[j] > midB); cB += __popcll(mmB[j]);
        }
        if (pA) {
            if (cA == 16) { copy8(selA, mmA); doneA = true; }
            else if (cA > 16) loA = midA; else hiA = midA;
        }
        if (pB) {
            if (cB == 16) { copy8(selB, mmB); doneB = true; }
            else if (cB > 16) loB = midB; else hiB = midB;
        }
    }
    if (!doneA) tie_fill(uA, selA, hiA);
    if (!doneB) tie_fill(uB, selB, hiB);
}

// ---------------------------------------------------------------------------
// weights: q_w,k_w -> fp16 hi+lo split; v_w,out_w -> fp16 single
// ---------------------------------------------------------------------------
__global__ __launch_bounds__(256) void convw_kernel(
    const float* __restrict__ q_w, const float* __restrict__ k_w,
    const float* __restrict__ v_w, const float* __restrict__ out_w,
    _Float16* __restrict__ qwh, _Float16* __restrict__ qwl,
    _Float16* __restrict__ kwh, _Float16* __restrict__ kwl,
    _Float16* __restrict__ vw16, _Float16* __restrict__ ow16)
{
    int idx = blockIdx.x * 256 + threadIdx.x;
    if (idx < 442368) {
        float x = q_w[idx];
        _Float16 hi = (_Float16)x;
        qwh[idx] = hi; qwl[idx] = (_Float16)(x - (float)hi);
    } else if (idx < 442368 + 147456) {
        int i = idx - 442368;
        float x = k_w[i];
        _Float16 hi = (_Float16)x;
        kwh[i] = hi; kwl[i] = (_Float16)(x - (float)hi);
    } else if (idx < 442368 + 294912) {
        int i = idx - 442368 - 147456;
        vw16[i] = (_Float16)v_w[i];
    } else {
        int i = idx - 442368 - 294912;
        ow16[i] = (_Float16)out_w[i];
    }
}

// ---------------------------------------------------------------------------
// eo = silu(emb) @ W^T + b
// ---------------------------------------------------------------------------
__global__ __launch_bounds__(256) void eo_kernel(
    const float* __restrict__ emb,
    const float* __restrict__ adaln_w, const float* __restrict__ adaln_b,
    const float* __restrict__ xfn_w,  const float* __restrict__ xfn_b,
    float* __restrict__ eo)
{
    int wid  = blockIdx.x * 4 + (threadIdx.x >> 6);
    int lane = threadIdx.x & 63;
    int l = wid >> 12;
    int rem = wid & 4095;
    int b = rem >> 10;
    int o = rem & 1023;
    const float* wrow = (l < 3) ? (adaln_w + ((size_t)(l * 1024 + o)) * 512)
                                : (xfn_w + (size_t)o * 512);
    const float* erow = emb + b * 512;
    float acc = 0.f;
    for (int d = lane; d < 512; d += 64) {
        float e = erow[d];
        float se = e / (1.f + __expf(-e));
        acc = fmaf(se, wrow[d], acc);
    }
    #pragma unroll
    for (int off = 32; off; off >>= 1) acc += __shfl_xor(acc, off, 64);
    if (lane == 0) {
        float bias = (l < 3) ? adaln_b[l * 1024 + o] : xfn_b[o];
        eo[wid] = acc + bias;
    }
}

// ---------------------------------------------------------------------------
// LayerNorm + modulation -> fp16 hi+lo planes; thread owns adjacent pair
// (float2 loads, packed 4B half2 stores)
// ---------------------------------------------------------------------------
__global__ __launch_bounds__(256) void ln_kernel(
    const float* __restrict__ x1, const float* __restrict__ x2,
    const float* __restrict__ x3, const float* __restrict__ xf,
    const float* __restrict__ eo,
    _Float16* __restrict__ xnqh, _Float16* __restrict__ xnql,
    _Float16* __restrict__ xfnh, _Float16* __restrict__ xfnl)
{
    int row = blockIdx.x;
    const float* src; const float* eorow; _Float16* dh; _Float16* dl;
    if (row < 6144) {
        int l = row >> 11, idx = row & 2047, b = idx >> 9;
        const float* xp = (l == 0) ? x1 : (l == 1) ? x2 : x3;
        src = xp + (size_t)idx * 512;
        eorow = eo + (size_t)(l * 4 + b) * 1024;
        dh = xnqh + (size_t)row * 512;
        dl = xnql + (size_t)row * 512;
    } else {
        int rr = row - 6144; int b = rr >> 12;
        src = xf + (size_t)rr * 512;
        eorow = eo + (size_t)(12 + b) * 1024;
        dh = xfnh + (size_t)rr * 512;
        dl = xfnl + (size_t)rr * 512;
    }
    int tid = threadIdx.x;
    float2 vv = *(const float2*)(src + 2 * tid);
    float s = vv.x + vv.y;
    float q = fmaf(vv.x, vv.x, vv.y * vv.y);
    #pragma unroll
    for (int off = 32; off; off >>= 1) {
        s += __shfl_xor(s, off, 64);
        q += __shfl_xor(q, off, 64);
    }
    __shared__ float red[8];
    int wv = tid >> 6, lane = tid & 63;
    if (lane == 0) { red[wv] = s; red[4 + wv] = q; }
    __syncthreads();
    s = red[0] + red[1] + red[2] + red[3];
    q = red[4] + red[5] + red[6] + red[7];
    float mu  = s * (1.f / 512.f);
    float var = q * (1.f / 512.f) - mu * mu;
    float rs  = 1.f / sqrtf(var + 1e-6f);
    float2 sc = *(const float2*)(eorow + 2 * tid);
    float2 sh = *(const float2*)(eorow + 512 + 2 * tid);
    float r0 = (vv.x - mu) * rs * (1.f + sc.x) + sh.x;
    float r1 = (vv.y - mu) * rs * (1.f + sc.y) + sh.y;
    _Float16 h0 = (_Float16)r0, h1 = (_Float16)r1;
    half2v H = {h0, h1};
    half2v L = {(_Float16)(r0 - (float)h0), (_Float16)(r1 - (float)h1)};
    *(half2v*)(dh + 2 * tid) = H;
    *(half2v*)(dl + 2 * tid) = L;
}

// ---------------------------------------------------------------------------
// fp16 MFMA GEMM, LDS-free, per-wave 32 x (NF*16) tile.
// MODE 0: Q-proj  SPLIT  (xnq 6144x512 @ qw -> Qb [bh][1536][36])
// MODE 1: K-proj  SPLIT  (xfn 16384x512 @ kw -> Kt [bh][36][512] transposed)
// MODE 2: V-proj  single (xfn 16384x512 @ vw -> Vb [bh][512][36])
// MODE 3: out-proj single (att16 [b][1536][288] @ ow -> d_out, A-rows remapped)
// SPLIT: acc = Ah@Wh + Ah@Wl + Al@Wh  (fp16 two-term; f32-grade result)
// ---------------------------------------------------------------------------
template<int NF, int MODE>
__global__ __launch_bounds__(256) void gemm16_kernel(
    const _Float16* __restrict__ Ah, const _Float16* __restrict__ Al,
    const _Float16* __restrict__ Wh, const _Float16* __restrict__ Wl,
    const float* __restrict__ bias,
    float* __restrict__ O0)
{
    constexpr bool SPLIT = (MODE == 0 || MODE == 1);
    const int Kd = (MODE == 3) ? 288 : 512;
    const int NT = (MODE == 0) ? 6 : (MODE == 3) ? 8 : 1;
    const int gw = blockIdx.x * 4 + (threadIdx.x >> 6);
    const int l  = threadIdx.x & 63;
    const int mt = gw / NT, nt = gw - mt * NT;
    const int row0 = mt * 32;
    const int col0 = nt * (NF * 16);
    const int lr = l & 15, lk = (l >> 4) * 8;

    int lsel = 0, h = 0;
    if (MODE == 0)                 { lsel = row0 >> 11; }
    else if (MODE == 1 || MODE == 2) { h = (row0 >> 9) & 7; }
    else                           { lsel = row0 >> 11; }

    size_t arow0;
    if (MODE == 3) {
        int rb = row0 & 2047, bb = rb >> 9, t0 = rb & 511;
        arow0 = (size_t)bb * 1536 + (size_t)lsel * 512 + t0;
    } else {
        arow0 = (size_t)row0;
    }

    const _Float16* aph = Ah + (arow0 + lr) * Kd + lk;
    const _Float16* apl = SPLIT ? (Al + (arow0 + lr) * Kd + lk) : nullptr;

    const _Float16* bph[NF];
    const _Float16* bpl[NF];
    #pragma unroll
    for (int f = 0; f < NF; ++f) {
        int c = col0 + f * 16 + lr;
        int wr;
        if (MODE == 0)      wr = lsel * 288 + c;
        else if (MODE == 3) wr = lsel * 512 + c;
        else                wr = h * 36 + (c < 36 ? c : 0);   // clamp; write masked
        bph[f] = Wh + (size_t)wr * Kd + lk;
        if (SPLIT) bpl[f] = Wl + (size_t)wr * Kd + lk;
    }

    f32x4 acc[2][NF];
    #pragma unroll
    for (int mi = 0; mi < 2; ++mi)
        #pragma unroll
        for (int f = 0; f < NF; ++f) acc[mi][f] = (f32x4){0.f, 0.f, 0.f, 0.f};

    for (int kk = 0; kk < Kd; kk += 32) {
        half8 a0h = *(const half8*)(aph + kk);
        half8 a1h = *(const half8*)(aph + (size_t)16 * Kd + kk);
        half8 a0l, a1l;
        if constexpr (SPLIT) {
            a0l = *(const half8*)(apl + kk);
            a1l = *(const half8*)(apl + (size_t)16 * Kd + kk);
        }
        #pragma unroll
        for (int f = 0; f < NF; ++f) {
            half8 bh_ = *(const half8*)(bph[f] + kk);
            acc[0][f] = __builtin_amdgcn_mfma_f32_16x16x32_f16(a0h, bh_, acc[0][f], 0, 0, 0);
            acc[1][f] = __builtin_amdgcn_mfma_f32_16x16x32_f16(a1h, bh_, acc[1][f], 0, 0, 0);
            if constexpr (SPLIT) {
                half8 bl_ = *(const half8*)(bpl[f] + kk);
                acc[0][f] = __builtin_amdgcn_mfma_f32_16x16x32_f16(a0h, bl_, acc[0][f], 0, 0, 0);
                acc[1][f] = __builtin_amdgcn_mfma_f32_16x16x32_f16(a1h, bl_, acc[1][f], 0, 0, 0);
                acc[0][f] = __builtin_amdgcn_mfma_f32_16x16x32_f16(a0l, bh_, acc[0][f], 0, 0, 0);
                acc[1][f] = __builtin_amdgcn_mfma_f32_16x16x32_f16(a1l, bh_, acc[1][f], 0, 0, 0);
            }
        }
    }

    #pragma unroll
    for (int mi = 0; mi < 2; ++mi) {
        int rbase = row0 + mi * 16 + (l >> 4) * 4;
        #pragma unroll
        for (int f = 0; f < NF; ++f) {
            int c = col0 + f * 16 + (l & 15);
            if (MODE == 0) {
                int hh = c / 36, hd = c - hh * 36;
                float bz = bias[lsel * 288 + c];
                #pragma unroll
                for (int j = 0; j < 4; ++j) {
                    int r = rbase + j;
                    int rb = r & 2047, bb2 = rb >> 9, t = rb & 511;
                    O0[(((size_t)bb2 * 8 + hh) * 1536 + lsel * 512 + t) * 36 + hd]
                        = acc[mi][f][j] + bz;
                }
            } else if (MODE == 1) {
                if (c < 36) {
                    int bb2 = row0 >> 12;
                    int n0 = rbase & 511;
                    float bz = bias[h * 36 + c];
                    float4 v4;
                    v4.x = acc[mi][f][0] + bz; v4.y = acc[mi][f][1] + bz;
                    v4.z = acc[mi][f][2] + bz; v4.w = acc[mi][f][3] + bz;
                    *(float4*)&O0[(((size_t)bb2 * 8 + h) * 36 + c) * 512 + n0] = v4;
                }
            } else if (MODE == 2) {
                if (c < 36) {
                    int bb2 = row0 >> 12;
                    int n0 = rbase & 511;
                    float bz = bias[h * 36 + c];
                    #pragma unroll
                    for (int j = 0; j < 4; ++j)
                        O0[(((size_t)bb2 * 8 + h) * 512 + n0 + j) * 36 + c]
                            = acc[mi][f][j] + bz;
                }
            } else {
                float bz = bias[lsel * 512 + c];
                #pragma unroll
                for (int j = 0; j < 4; ++j) {
                    int r = rbase + j;
                    int rb = r & 2047, bb2 = rb >> 9, t = rb & 511;
                    O0[(size_t)lsel * 1048576 + ((size_t)bb2 * 512 + t) * 512 + c]
                        = acc[mi][f][j] + bz;
                }
            }
        }
    }
}

// ---------------------------------------------------------------------------
// Attention: grid 32bh x 48 chunks, 512 thr, one 32-row pass per block.
// u_noise prefetched before QK; paired bisection; ballot-rank compaction +
// fixed 16-iter PV gather. Writes att16 fp16 [b][1536][288].
// ---------------------------------------------------------------------------
__global__ __launch_bounds__(512, 4) void attn_kernel(
    const float* __restrict__ Qb, const float* __restrict__ Kt,
    const float* __restrict__ Vb, const float* __restrict__ un,
    _Float16* __restrict__ att16)
{
    __shared__ float Q_s[36 * 32];
    __shared__ float CmpW[8][2][2][16];
    __shared__ int   CmpN[8][2][2][16];

    const int tid = threadIdx.x;
    const int bh = blockIdx.x / 48;
    const int chunk = blockIdx.x - bh * 48;
    const int t0p = chunk * 32;
    const int b = bh >> 3, h = bh & 7;
    const int l = tid & 63;
    const int wv = tid >> 6;
    const int w4 = wv * 4;
    const int dpv = l & 31, halfw = l >> 5;
    const float S6 = 1.0f / 6.0f;

    // prefetch all u_noise for this wave's 4 rows (8 float4/lane) — issued
    // before QK so HBM latency hides under the 36-iter QK loop
    float4 uPre[4][2];
    {
        const float* ubase = un + ((size_t)bh * 1536 + t0p + w4) * 512;
        #pragma unroll
        for (int r = 0; r < 4; ++r) {
            uPre[r][0] = FI4(&ubase[(size_t)r * 512 + l * 4]);
            uPre[r][1] = FI4(&ubase[(size_t)r * 512 + 256 + l * 4]);
        }
    }

    for (int idx = tid; idx < 32 * 36; idx += 512) {
        int r = idx & 31, dd = idx >> 5;
        Q_s[dd * 32 + r] = Qb[((size_t)bh * 1536 + t0p + r) * 36 + dd];
    }
    __syncthreads();

    const float* Ktbh = Kt + (size_t)bh * 18432;
    const float* Vbh  = Vb + (size_t)bh * 18432;

    // QK^T: acc[4 rows][8 slots], slot j -> n = (j>>2)*256 + l*4 + (j&3)
    float acc[4][8];
    #pragma unroll
    for (int r = 0; r < 4; ++r)
        #pragma unroll
        for (int j = 0; j < 8; ++j) acc[r][j] = 0.f;

    #pragma unroll 9
    for (int dd = 0; dd < 36; ++dd) {
        float4 q   = FI4(&Q_s[dd * 32 + w4]);
        const float* ktr = Ktbh + dd * 512;
        float4 ka  = FI4(&ktr[l * 4]);
        float4 kb2 = FI4(&ktr[256 + l * 4]);
        float qv[4] = {q.x, q.y, q.z, q.w};
        float kv[8] = {ka.x, ka.y, ka.z, ka.w, kb2.x, kb2.y, kb2.z, kb2.w};
        #pragma unroll
        for (int r = 0; r < 4; ++r)
            #pragma unroll
            for (int j = 0; j < 8; ++j)
                acc[r][j] = fmaf(qv[r], kv[j], acc[r][j]);
    }

    #pragma unroll
    for (int pr = 0; pr < 2; ++pr) {
        const int ta = t0p + w4 + pr * 2;

        float sa[8], sb[8];
        {
            float4 u0 = uPre[pr * 2][0], u1 = uPre[pr * 2][1];
            sa[0] = fmaf(acc[pr*2][0], S6, gumbelf(u0.x));
            sa[1] = fmaf(acc[pr*2][1], S6, gumbelf(u0.y));
            sa[2] = fmaf(acc[pr*2][2], S6, gumbelf(u0.z));
            sa[3] = fmaf(acc[pr*2][3], S6, gumbelf(u0.w));
            sa[4] = fmaf(acc[pr*2][4], S6, gumbelf(u1.x));
            sa[5] = fmaf(acc[pr*2][5], S6, gumbelf(u1.y));
            sa[6] = fmaf(acc[pr*2][6], S6, gumbelf(u1.z));
            sa[7] = fmaf(acc[pr*2][7], S6, gumbelf(u1.w));
        }
        {
            float4 u0 = uPre[pr * 2 + 1][0], u1 = uPre[pr * 2 + 1][1];
            sb[0] = fmaf(acc[pr*2+1][0], S6, gumbelf(u0.x));
            sb[1] = fmaf(acc[pr*2+1][1], S6, gumbelf(u0.y));
            sb[2] = fmaf(acc[pr*2+1][2], S6, gumbelf(u0.z));
            sb[3] = fmaf(acc[pr*2+1][3], S6, gumbelf(u0.w));
            sb[4] = fmaf(acc[pr*2+1][4], S6, gumbelf(u1.x));
            sb[5] = fmaf(acc[pr*2+1][5], S6, gumbelf(u1.y));
            sb[6] = fmaf(acc[pr*2+1][6], S6, gumbelf(u1.z));
            sb[7] = fmaf(acc[pr*2+1][7], S6, gumbelf(u1.w));
        }

        unsigned ua32[8], ub32[8];
        float mA = sa[0], mB = sb[0];
        #pragma unroll
        for (int j = 0; j < 8; ++j) {
            ua32[j] = ordkey(sa[j]); ub32[j] = ordkey(sb[j]);
            mA = fmaxf(mA, sa[j]); mB = fmaxf(mB, sb[j]);
        }
        mA = wave_max_bcast(mA);
        mB = wave_max_bcast(mB);

        unsigned long long selA[8], selB[8];
        select16_pair(ua32, ub32, selA, selB,
                      ordkey(mA - 28.0f), ordkey(mA),
                      ordkey(mB - 28.0f), ordkey(mB));

        // weights = exp(s - m); ratio identical to softmax
        float eAr[8], eBr[8], psA = 0.f, psB = 0.f;
        #pragma unroll
        for (int j = 0; j < 8; ++j) {
            float exa = __expf(sa[j] - mA);
            float exb = __expf(sb[j] - mB);
            eAr[j] = ((selA[j] >> l) & 1ull) ? exa : 0.f;
            eBr[j] = ((selB[j] >> l) & 1ull) ? exb : 0.f;
            psA += eAr[j]; psB += eBr[j];
        }
        float sumA = wave_sum_bcast(psA);
        float sumB = wave_sum_bcast(psB);

        // compact 16 (n, w) winners per row into LDS (ballot-rank)
        {
            int baseA = 0, baseB = 0;
            #pragma unroll
            for (int j = 0; j < 8; ++j) {
                unsigned long long ma = selA[j], mb = selB[j];
                int nj = ((j >> 2) << 8) + l * 4 + (j & 3);
                if ((ma >> l) & 1ull) {
                    int rank = baseA + mbcnt64(ma);
                    CmpN[wv][pr][0][rank] = nj;
                    CmpW[wv][pr][0][rank] = eAr[j];
                }
                if ((mb >> l) & 1ull) {
                    int rank = baseB + mbcnt64(mb);
                    CmpN[wv][pr][1][rank] = nj;
                    CmpW[wv][pr][1][rank] = eBr[j];
                }
                baseA += __popcll(ma); baseB += __popcll(mb);
            }
        }
        asm volatile("s_waitcnt lgkmcnt(0)" ::: "memory");

        // fixed 16-iter gather: independent V-row loads, full ILP
        float od = 0.f, od2 = 0.f;
        #pragma unroll
        for (int k = 0; k < 16; ++k) {
            int nn  = CmpN[wv][pr][halfw][k];
            float w = CmpW[wv][pr][halfw][k];
            const float* vr = Vbh + (size_t)nn * 36;
            od = fmaf(w, vr[dpv], od);
            if (dpv < 4) od2 = fmaf(w, vr[32 + dpv], od2);
        }

        float invs = 1.0f / (halfw ? sumB : sumA);
        int t = ta + halfw;
        _Float16* orow = att16 + ((size_t)b * 1536 + t) * 288 + h * 36;
        orow[dpv] = (_Float16)(od * invs);
        if (dpv < 4) orow[32 + dpv] = (_Float16)(od2 * invs);
    }
}

// ---------------------------------------------------------------------------
extern "C" void kernel_launch(void* const* d_in, const int* in_sizes, int n_in,
                              void* d_out, int out_size, void* d_ws, size_t ws_size,
                              hipStream_t stream)
{
    (void)in_sizes; (void)n_in; (void)out_size; (void)ws_size;
    const float* x1      = (const float*)d_in[0];
    const float* x2      = (const float*)d_in[1];
    const float* x3      = (const float*)d_in[2];
    const float* xf      = (const float*)d_in[3];
    const float* emb     = (const float*)d_in[4];
    const float* un      = (const float*)d_in[5];
    const float* adaln_w = (const float*)d_in[6];
    const float* adaln_b = (const float*)d_in[7];
    const float* xfn_w   = (const float*)d_in[8];
    const float* xfn_b   = (const float*)d_in[9];
    const float* q_w     = (const float*)d_in[10];
    const float* q_b     = (const float*)d_in[11];
    const float* k_w     = (const float*)d_in[12];
    const float* k_b     = (const float*)d_in[13];
    const float* v_w     = (const float*)d_in[14];
    const float* v_b     = (const float*)d_in[15];
    const float* out_w   = (const float*)d_in[16];
    const float* out_b   = (const float*)d_in[17];
    float* out = (float*)d_out;

    float* ws = (float*)d_ws;
    float* eo = ws;                          // 16,384 f32
    float* Qb = eo + 16384;                  // 1,769,472 f32
    float* Kt = Qb + 1769472;                // 589,824 f32  [bh][36][512]
    float* Vb = Kt + 589824;                 // 589,824 f32  [bh][512][36]
    _Float16* xnqh = (_Float16*)(Vb + 589824);   // 3,145,728 h
    _Float16* xnql = xnqh + 3145728;
    _Float16* xfnh = xnql + 3145728;         // 8,388,608 h
    _Float16* xfnl = xfnh + 8388608;
    _Float16* att16 = xfnl + 8388608;        // 1,769,472 h
    _Float16* qwh  = att16 + 1769472;        // 442,368 h
    _Float16* qwl  = qwh + 442368;
    _Float16* kwh  = qwl + 442368;           // 147,456 h
    _Float16* kwl  = kwh + 147456;
    _Float16* vw16 = kwl + 147456;           // 147,456 h
    _Float16* ow16 = vw16 + 147456;          // 442,368 h

    convw_kernel<<<4608, 256, 0, stream>>>(q_w, k_w, v_w, out_w,
                                           qwh, qwl, kwh, kwl, vw16, ow16);
    eo_kernel<<<4096, 256, 0, stream>>>(emb, adaln_w, adaln_b, xfn_w, xfn_b, eo);
    ln_kernel<<<22528, 256, 0, stream>>>(x1, x2, x3, xf, eo, xnqh, xnql, xfnh, xfnl);
    gemm16_kernel<3, 0><<<288, 256, 0, stream>>>(xnqh, xnql, qwh, qwl, q_b, Qb);
    gemm16_kernel<3, 1><<<128, 256, 0, stream>>>(xfnh, xfnl, kwh, kwl, k_b, Kt);
    gemm16_kernel<3, 2><<<128, 256, 0, stream>>>(xfnh, nullptr, vw16, nullptr, v_b, Vb);
    attn_kernel<<<1536, 512, 0, stream>>>(Qb, Kt, Vb, un, att16);
    gemm16_kernel<4, 3><<<384, 256, 0, stream>>>(att16, nullptr, ow16, nullptr, out_b, out);
}

// Round 11
// 209.565 us; speedup vs baseline: 1.1308x; 1.1308x over previous
//
#include <hip/hip_runtime.h>
#include <math.h>

#define FI4(p) (*(const float4*)(p))

typedef _Float16 half8 __attribute__((ext_vector_type(8)));
typedef _Float16 half2v __attribute__((ext_vector_type(2)));
typedef float f32x4 __attribute__((ext_vector_type(4)));

__device__ __forceinline__ float gumbelf(float u) {
    return -__logf(-__logf(u + 1e-9f) + 1e-9f);
}

template<int CTRL>
__device__ __forceinline__ int dppmov(int v) {
    return __builtin_amdgcn_update_dpp(v, v, CTRL, 0xF, 0xF, false);
}
__device__ __forceinline__ float wave_max_bcast(float v) {
    v = fmaxf(v, __int_as_float(dppmov<0xB1>(__float_as_int(v))));
    v = fmaxf(v, __int_as_float(dppmov<0x4E>(__float_as_int(v))));
    v = fmaxf(v, __int_as_float(dppmov<0x141>(__float_as_int(v))));
    v = fmaxf(v, __int_as_float(dppmov<0x140>(__float_as_int(v))));
    v = fmaxf(v, __int_as_float(dppmov<0x142>(__float_as_int(v))));
    v = fmaxf(v, __int_as_float(dppmov<0x143>(__float_as_int(v))));
    return __int_as_float(__builtin_amdgcn_readlane(__float_as_int(v), 63));
}
__device__ __forceinline__ float wave_sum_bcast(float v) {
    v += __int_as_float(dppmov<0xB1>(__float_as_int(v)));
    v += __int_as_float(dppmov<0x4E>(__float_as_int(v)));
    v += __int_as_float(dppmov<0x141>(__float_as_int(v)));
    v += __int_as_float(dppmov<0x140>(__float_as_int(v)));
    v += __int_as_float(dppmov<0x142>(__float_as_int(v)));
    v += __int_as_float(dppmov<0x143>(__float_as_int(v)));
    return __int_as_float(__builtin_amdgcn_readlane(__float_as_int(v), 63));
}

__device__ __forceinline__ unsigned ordkey(float f) {
    unsigned x = __float_as_uint(f);
    return x ^ ((unsigned)((int)x >> 31) | 0x80000000u);
}

__device__ __forceinline__ int mbcnt64(unsigned long long m) {
    return __builtin_amdgcn_mbcnt_hi((unsigned)(m >> 32),
           __builtin_amdgcn_mbcnt_lo((unsigned)m, 0));
}

__device__ __forceinline__ void copy8(unsigned long long* dst, const unsigned long long* src) {
    #pragma unroll
    for (int j = 0; j < 8; ++j) dst[j] = src[j];
}

// ties at key == hi filled by smallest n; n = (j>>2)*256 + lane*4 + (j&3)
__device__ __forceinline__ void tie_fill(const unsigned* u, unsigned long long* sel, unsigned hi)
{
    unsigned long long eq[8];
    int mcnt = 0;
    #pragma unroll
    for (int j = 0; j < 8; ++j) {
        sel[j] = __ballot(u[j] > hi);
        eq[j]  = __ballot(u[j] == hi);
        mcnt += __popcll(sel[j]);
    }
    int r = 16 - mcnt;
    #pragma unroll
    for (int jhi = 0; jhi < 2; ++jhi) {
        if (r > 0) {
            unsigned long long any = eq[jhi*4] | eq[jhi*4+1] | eq[jhi*4+2] | eq[jhi*4+3];
            while (any && r > 0) {
                int lane = (int)__builtin_ctzll(any); any &= any - 1;
                #pragma unroll
                for (int jlo = 0; jlo < 4; ++jlo) {
                    int j2 = jhi * 4 + jlo;
                    if (r > 0 && ((eq[j2] >> lane) & 1ull)) { sel[j2] |= 1ull << lane; --r; }
                }
            }
        }
    }
}

// Dual top-16 bisection: rows A and B searched in lockstep so the two
// dependent ballot->popcount->branch chains overlap (16 ballots in flight).
__device__ __forceinline__ void select16_pair(
    const unsigned* uA, const unsigned* uB,
    unsigned long long* selA, unsigned long long* selB,
    unsigned loA, unsigned hiA, unsigned loB, unsigned hiB)
{
    bool doneA = false, doneB = false;
    {
        unsigned long long mmA[8], mmB[8];
        int cA = 0, cB = 0;
        #pragma unroll
        for (int j = 0; j < 8; ++j) {
            mmA[j] = __ballot(uA[j] > loA); cA += __popcll(mmA[j]);
            mmB[j] = __ballot(uB[j] > loB); cB += __popcll(mmB[j]);
        }
        if (cA == 16) { copy8(selA, mmA); doneA = true; }
        else if (cA < 16) loA = 0u;   // ordkey(finite) > 0 => cnt(>0) = 512 > 16
        if (cB == 16) { copy8(selB, mmB); doneB = true; }
        else if (cB < 16) loB = 0u;
    }
    while ((!doneA && hiA - loA > 1u) || (!doneB && hiB - loB > 1u)) {
        bool pA = !doneA && (hiA - loA > 1u);
        bool pB = !doneB && (hiB - loB > 1u);
        unsigned midA = loA + ((hiA - loA) >> 1);
        unsigned midB = loB + ((hiB - loB) >> 1);
        unsigned long long mmA[8], mmB[8];
        int cA = 0, cB = 0;
        #pragma unroll
        for (int j = 0; j < 8; ++j) {
            mmA[j] = __ballot(uA[j] > midA); cA += __popcll(mmA[j]);
            mmB[j] = __ballot(uB[j] > midB); cB += __popcll(mmB[j]);
        }
        if (pA) {
            if (cA == 16) { copy8(selA, mmA); doneA = true; }
            else if (cA > 16) loA = midA; else hiA = midA;
        }
        if (pB) {
            if (cB == 16) { copy8(selB, mmB); doneB = true; }
            else if (cB > 16) loB = midB; else hiB = midB;
        }
    }
    if (!doneA) tie_fill(uA, selA, hiA);
    if (!doneB) tie_fill(uB, selB, hiB);
}

// ---------------------------------------------------------------------------
// Fused prep: blocks [0,4608) convert weights (q/k hi+lo split, v/out single);
// blocks [4608,8704) compute eo = silu(emb) @ W^T + b
// ---------------------------------------------------------------------------
__global__ __launch_bounds__(256) void prep_kernel(
    const float* __restrict__ q_w, const float* __restrict__ k_w,
    const float* __restrict__ v_w, const float* __restrict__ out_w,
    const float* __restrict__ emb,
    const float* __restrict__ adaln_w, const float* __restrict__ adaln_b,
    const float* __restrict__ xfn_w,  const float* __restrict__ xfn_b,
    _Float16* __restrict__ qwh, _Float16* __restrict__ qwl,
    _Float16* __restrict__ kwh, _Float16* __restrict__ kwl,
    _Float16* __restrict__ vw16, _Float16* __restrict__ ow16,
    float* __restrict__ eo)
{
    if (blockIdx.x < 4608) {
        int idx = blockIdx.x * 256 + threadIdx.x;
        if (idx < 442368) {
            float x = q_w[idx];
            _Float16 hi = (_Float16)x;
            qwh[idx] = hi; qwl[idx] = (_Float16)(x - (float)hi);
        } else if (idx < 442368 + 147456) {
            int i = idx - 442368;
            float x = k_w[i];
            _Float16 hi = (_Float16)x;
            kwh[i] = hi; kwl[i] = (_Float16)(x - (float)hi);
        } else if (idx < 442368 + 294912) {
            int i = idx - 442368 - 147456;
            vw16[i] = (_Float16)v_w[i];
        } else {
            int i = idx - 442368 - 294912;
            ow16[i] = (_Float16)out_w[i];
        }
    } else {
        int wid  = (blockIdx.x - 4608) * 4 + (threadIdx.x >> 6);
        int lane = threadIdx.x & 63;
        int l = wid >> 12;
        int rem = wid & 4095;
        int b = rem >> 10;
        int o = rem & 1023;
        const float* wrow = (l < 3) ? (adaln_w + ((size_t)(l * 1024 + o)) * 512)
                                    : (xfn_w + (size_t)o * 512);
        const float* erow = emb + b * 512;
        float acc = 0.f;
        for (int d = lane; d < 512; d += 64) {
            float e = erow[d];
            float se = e / (1.f + __expf(-e));
            acc = fmaf(se, wrow[d], acc);
        }
        #pragma unroll
        for (int off = 32; off; off >>= 1) acc += __shfl_xor(acc, off, 64);
        if (lane == 0) {
            float bias = (l < 3) ? adaln_b[l * 1024 + o] : xfn_b[o];
            eo[wid] = acc + bias;
        }
    }
}

// ---------------------------------------------------------------------------
// LayerNorm + modulation -> fp16 hi+lo planes; thread owns adjacent pair
// ---------------------------------------------------------------------------
__global__ __launch_bounds__(256) void ln_kernel(
    const float* __restrict__ x1, const float* __restrict__ x2,
    const float* __restrict__ x3, const float* __restrict__ xf,
    const float* __restrict__ eo,
    _Float16* __restrict__ xnqh, _Float16* __restrict__ xnql,
    _Float16* __restrict__ xfnh, _Float16* __restrict__ xfnl)
{
    int row = blockIdx.x;
    const float* src; const float* eorow; _Float16* dh; _Float16* dl;
    if (row < 6144) {
        int l = row >> 11, idx = row & 2047, b = idx >> 9;
        const float* xp = (l == 0) ? x1 : (l == 1) ? x2 : x3;
        src = xp + (size_t)idx * 512;
        eorow = eo + (size_t)(l * 4 + b) * 1024;
        dh = xnqh + (size_t)row * 512;
        dl = xnql + (size_t)row * 512;
    } else {
        int rr = row - 6144; int b = rr >> 12;
        src = xf + (size_t)rr * 512;
        eorow = eo + (size_t)(12 + b) * 1024;
        dh = xfnh + (size_t)rr * 512;
        dl = xfnl + (size_t)rr * 512;
    }
    int tid = threadIdx.x;
    float2 vv = *(const float2*)(src + 2 * tid);
    float s = vv.x + vv.y;
    float q = fmaf(vv.x, vv.x, vv.y * vv.y);
    #pragma unroll
    for (int off = 32; off; off >>= 1) {
        s += __shfl_xor(s, off, 64);
        q += __shfl_xor(q, off, 64);
    }
    __shared__ float red[8];
    int wv = tid >> 6, lane = tid & 63;
    if (lane == 0) { red[wv] = s; red[4 + wv] = q; }
    __syncthreads();
    s = red[0] + red[1] + red[2] + red[3];
    q = red[4] + red[5] + red[6] + red[7];
    float mu  = s * (1.f / 512.f);
    float var = q * (1.f / 512.f) - mu * mu;
    float rs  = 1.f / sqrtf(var + 1e-6f);
    float2 sc = *(const float2*)(eorow + 2 * tid);
    float2 sh = *(const float2*)(eorow + 512 + 2 * tid);
    float r0 = (vv.x - mu) * rs * (1.f + sc.x) + sh.x;
    float r1 = (vv.y - mu) * rs * (1.f + sc.y) + sh.y;
    _Float16 h0 = (_Float16)r0, h1 = (_Float16)r1;
    half2v H = {h0, h1};
    half2v L = {(_Float16)(r0 - (float)h0), (_Float16)(r1 - (float)h1)};
    *(half2v*)(dh + 2 * tid) = H;
    *(half2v*)(dl + 2 * tid) = L;
}

// ---------------------------------------------------------------------------
// fp16 MFMA GEMM, LDS-free, per-wave 32 x (NF*16) tile.
// MODE 0: Q-proj  SPLIT  (xnq 6144x512 @ qw -> Qb [bh][1536][36])
// MODE 1: K-proj  SPLIT  (xfn 16384x512 @ kw -> Kt [bh][36][512] transposed)
// MODE 2: V-proj  single (xfn 16384x512 @ vw -> Vb [bh][512][36])
// MODE 3: out-proj single (att16 [b][1536][288] @ ow -> d_out, A-rows remapped)
// SPLIT: acc = Ah@Wh + Ah@Wl + Al@Wh  (fp16 two-term; f32-grade result)
// ---------------------------------------------------------------------------
template<int NF, int MODE>
__global__ __launch_bounds__(256) void gemm16_kernel(
    const _Float16* __restrict__ Ah, const _Float16* __restrict__ Al,
    const _Float16* __restrict__ Wh, const _Float16* __restrict__ Wl,
    const float* __restrict__ bias,
    float* __restrict__ O0)
{
    constexpr bool SPLIT = (MODE == 0 || MODE == 1);
    const int Kd = (MODE == 3) ? 288 : 512;
    const int NT = (MODE == 0) ? 6 : (MODE == 3) ? 8 : 1;
    const int gw = blockIdx.x * 4 + (threadIdx.x >> 6);
    const int l  = threadIdx.x & 63;
    const int mt = gw / NT, nt = gw - mt * NT;
    const int row0 = mt * 32;
    const int col0 = nt * (NF * 16);
    const int lr = l & 15, lk = (l >> 4) * 8;

    int lsel = 0, h = 0;
    if (MODE == 0)                 { lsel = row0 >> 11; }
    else if (MODE == 1 || MODE == 2) { h = (row0 >> 9) & 7; }
    else                           { lsel = row0 >> 11; }

    size_t arow0;
    if (MODE == 3) {
        int rb = row0 & 2047, bb = rb >> 9, t0 = rb & 511;
        arow0 = (size_t)bb * 1536 + (size_t)lsel * 512 + t0;
    } else {
        arow0 = (size_t)row0;
    }

    const _Float16* aph = Ah + (arow0 + lr) * Kd + lk;
    const _Float16* apl = SPLIT ? (Al + (arow0 + lr) * Kd + lk) : nullptr;

    const _Float16* bph[NF];
    const _Float16* bpl[NF];
    #pragma unroll
    for (int f = 0; f < NF; ++f) {
        int c = col0 + f * 16 + lr;
        int wr;
        if (MODE == 0)      wr = lsel * 288 + c;
        else if (MODE == 3) wr = lsel * 512 + c;
        else                wr = h * 36 + (c < 36 ? c : 0);   // clamp; write masked
        bph[f] = Wh + (size_t)wr * Kd + lk;
        if (SPLIT) bpl[f] = Wl + (size_t)wr * Kd + lk;
    }

    f32x4 acc[2][NF];
    #pragma unroll
    for (int mi = 0; mi < 2; ++mi)
        #pragma unroll
        for (int f = 0; f < NF; ++f) acc[mi][f] = (f32x4){0.f, 0.f, 0.f, 0.f};

    for (int kk = 0; kk < Kd; kk += 32) {
        half8 a0h = *(const half8*)(aph + kk);
        half8 a1h = *(const half8*)(aph + (size_t)16 * Kd + kk);
        half8 a0l, a1l;
        if constexpr (SPLIT) {
            a0l = *(const half8*)(apl + kk);
            a1l = *(const half8*)(apl + (size_t)16 * Kd + kk);
        }
        #pragma unroll
        for (int f = 0; f < NF; ++f) {
            half8 bh_ = *(const half8*)(bph[f] + kk);
            acc[0][f] = __builtin_amdgcn_mfma_f32_16x16x32_f16(a0h, bh_, acc[0][f], 0, 0, 0);
            acc[1][f] = __builtin_amdgcn_mfma_f32_16x16x32_f16(a1h, bh_, acc[1][f], 0, 0, 0);
            if constexpr (SPLIT) {
                half8 bl_ = *(const half8*)(bpl[f] + kk);
                acc[0][f] = __builtin_amdgcn_mfma_f32_16x16x32_f16(a0h, bl_, acc[0][f], 0, 0, 0);
                acc[1][f] = __builtin_amdgcn_mfma_f32_16x16x32_f16(a1h, bl_, acc[1][f], 0, 0, 0);
                acc[0][f] = __builtin_amdgcn_mfma_f32_16x16x32_f16(a0l, bh_, acc[0][f], 0, 0, 0);
                acc[1][f] = __builtin_amdgcn_mfma_f32_16x16x32_f16(a1l, bh_, acc[1][f], 0, 0, 0);
            }
        }
    }

    #pragma unroll
    for (int mi = 0; mi < 2; ++mi) {
        int rbase = row0 + mi * 16 + (l >> 4) * 4;
        #pragma unroll
        for (int f = 0; f < NF; ++f) {
            int c = col0 + f * 16 + (l & 15);
            if (MODE == 0) {
                int hh = c / 36, hd = c - hh * 36;
                float bz = bias[lsel * 288 + c];
                #pragma unroll
                for (int j = 0; j < 4; ++j) {
                    int r = rbase + j;
                    int rb = r & 2047, bb2 = rb >> 9, t = rb & 511;
                    O0[(((size_t)bb2 * 8 + hh) * 1536 + lsel * 512 + t) * 36 + hd]
                        = acc[mi][f][j] + bz;
                }
            } else if (MODE == 1) {
                if (c < 36) {
                    int bb2 = row0 >> 12;
                    int n0 = rbase & 511;
                    float bz = bias[h * 36 + c];
                    float4 v4;
                    v4.x = acc[mi][f][0] + bz; v4.y = acc[mi][f][1] + bz;
                    v4.z = acc[mi][f][2] + bz; v4.w = acc[mi][f][3] + bz;
                    *(float4*)&O0[(((size_t)bb2 * 8 + h) * 36 + c) * 512 + n0] = v4;
                }
            } else if (MODE == 2) {
                if (c < 36) {
                    int bb2 = row0 >> 12;
                    int n0 = rbase & 511;
                    float bz = bias[h * 36 + c];
                    #pragma unroll
                    for (int j = 0; j < 4; ++j)
                        O0[(((size_t)bb2 * 8 + h) * 512 + n0 + j) * 36 + c]
                            = acc[mi][f][j] + bz;
                }
            } else {
                float bz = bias[lsel * 512 + c];
                #pragma unroll
                for (int j = 0; j < 4; ++j) {
                    int r = rbase + j;
                    int rb = r & 2047, bb2 = rb >> 9, t = rb & 511;
                    O0[(size_t)lsel * 1048576 + ((size_t)bb2 * 512 + t) * 512 + c]
                        = acc[mi][f][j] + bz;
                }
            }
        }
    }
}

// ---------------------------------------------------------------------------
// Attention: 1536 blocks, XCD-swizzled so all 48 chunks of one bh land on one
// XCD (Kt/Vb L2-resident). u_noise loaded late (inline, per row-pair — early
// prefetch thrashes L2, R9 lesson). Paired bisection; ballot-rank compaction
// + fixed 16-iter PV gather. Writes att16 fp16 [b][1536][288].
// ---------------------------------------------------------------------------
__global__ __launch_bounds__(512, 4) void attn_kernel(
    const float* __restrict__ Qb, const float* __restrict__ Kt,
    const float* __restrict__ Vb, const float* __restrict__ un,
    _Float16* __restrict__ att16)
{
    __shared__ float Q_s[36 * 32];
    __shared__ float CmpW[8][2][2][16];
    __shared__ int   CmpN[8][2][2][16];

    const int tid = threadIdx.x;
    // XCD swizzle: 1536 % 8 == 0 -> bijective; same-bh chunks share an XCD L2
    const int bid = ((int)blockIdx.x & 7) * 192 + ((int)blockIdx.x >> 3);
    const int bh = bid / 48;
    const int chunk = bid - bh * 48;
    const int t0p = chunk * 32;
    const int b = bh >> 3, h = bh & 7;
    const int l = tid & 63;
    const int wv = tid >> 6;
    const int w4 = wv * 4;
    const int dpv = l & 31, halfw = l >> 5;
    const float S6 = 1.0f / 6.0f;

    for (int idx = tid; idx < 32 * 36; idx += 512) {
        int r = idx & 31, dd = idx >> 5;
        Q_s[dd * 32 + r] = Qb[((size_t)bh * 1536 + t0p + r) * 36 + dd];
    }
    __syncthreads();

    const float* Ktbh = Kt + (size_t)bh * 18432;
    const float* Vbh  = Vb + (size_t)bh * 18432;

    // QK^T: acc[4 rows][8 slots], slot j -> n = (j>>2)*256 + l*4 + (j&3)
    float acc[4][8];
    #pragma unroll
    for (int r = 0; r < 4; ++r)
        #pragma unroll
        for (int j = 0; j < 8; ++j) acc[r][j] = 0.f;

    #pragma unroll 6
    for (int dd = 0; dd < 36; ++dd) {
        float4 q   = FI4(&Q_s[dd * 32 + w4]);
        const float* ktr = Ktbh + dd * 512;
        float4 ka  = FI4(&ktr[l * 4]);
        float4 kb2 = FI4(&ktr[256 + l * 4]);
        float qv[4] = {q.x, q.y, q.z, q.w};
        float kv[8] = {ka.x, ka.y, ka.z, ka.w, kb2.x, kb2.y, kb2.z, kb2.w};
        #pragma unroll
        for (int r = 0; r < 4; ++r)
            #pragma unroll
            for (int j = 0; j < 8; ++j)
                acc[r][j] = fmaf(qv[r], kv[j], acc[r][j]);
    }

    #pragma unroll
    for (int pr = 0; pr < 2; ++pr) {
        const int ta = t0p + w4 + pr * 2;

        float sa[8], sb[8];
        {
            const float* ua = un + ((size_t)bh * 1536 + ta) * 512;
            float4 u0 = FI4(&ua[l * 4]);
            float4 u1 = FI4(&ua[256 + l * 4]);
            sa[0] = fmaf(acc[pr*2][0], S6, gumbelf(u0.x));
            sa[1] = fmaf(acc[pr*2][1], S6, gumbelf(u0.y));
            sa[2] = fmaf(acc[pr*2][2], S6, gumbelf(u0.z));
            sa[3] = fmaf(acc[pr*2][3], S6, gumbelf(u0.w));
            sa[4] = fmaf(acc[pr*2][4], S6, gumbelf(u1.x));
            sa[5] = fmaf(acc[pr*2][5], S6, gumbelf(u1.y));
            sa[6] = fmaf(acc[pr*2][6], S6, gumbelf(u1.z));
            sa[7] = fmaf(acc[pr*2][7], S6, gumbelf(u1.w));
        }
        {
            const float* ub = un + ((size_t)bh * 1536 + ta + 1) * 512;
            float4 u0 = FI4(&ub[l * 4]);
            float4 u1 = FI4(&ub[256 + l * 4]);
            sb[0] = fmaf(acc[pr*2+1][0], S6, gumbelf(u0.x));
            sb[1] = fmaf(acc[pr*2+1][1], S6, gumbelf(u0.y));
            sb[2] = fmaf(acc[pr*2+1][2], S6, gumbelf(u0.z));
            sb[3] = fmaf(acc[pr*2+1][3], S6, gumbelf(u0.w));
            sb[4] = fmaf(acc[pr*2+1][4], S6, gumbelf(u1.x));
            sb[5] = fmaf(acc[pr*2+1][5], S6, gumbelf(u1.y));
            sb[6] = fmaf(acc[pr*2+1][6], S6, gumbelf(u1.z));
            sb[7] = fmaf(acc[pr*2+1][7], S6, gumbelf(u1.w));
        }

        unsigned ua32[8], ub32[8];
        float mA = sa[0], mB = sb[0];
        #pragma unroll
        for (int j = 0; j < 8; ++j) {
            ua32[j] = ordkey(sa[j]); ub32[j] = ordkey(sb[j]);
            mA = fmaxf(mA, sa[j]); mB = fmaxf(mB, sb[j]);
        }
        mA = wave_max_bcast(mA);
        mB = wave_max_bcast(mB);

        unsigned long long selA[8], selB[8];
        select16_pair(ua32, ub32, selA, selB,
                      ordkey(mA - 28.0f), ordkey(mA),
                      ordkey(mB - 28.0f), ordkey(mB));

        // weights = exp(s - m); ratio identical to softmax
        float eAr[8], eBr[8], psA = 0.f, psB = 0.f;
        #pragma unroll
        for (int j = 0; j < 8; ++j) {
            float exa = __expf(sa[j] - mA);
            float exb = __expf(sb[j] - mB);
            eAr[j] = ((selA[j] >> l) & 1ull) ? exa : 0.f;
            eBr[j] = ((selB[j] >> l) & 1ull) ? exb : 0.f;
            psA += eAr[j]; psB += eBr[j];
        }
        float sumA = wave_sum_bcast(psA);
        float sumB = wave_sum_bcast(psB);

        // compact 16 (n, w) winners per row into LDS (ballot-rank)
        {
            int baseA = 0, baseB = 0;
            #pragma unroll
            for (int j = 0; j < 8; ++j) {
                unsigned long long ma = selA[j], mb = selB[j];
                int nj = ((j >> 2) << 8) + l * 4 + (j & 3);
                if ((ma >> l) & 1ull) {
                    int rank = baseA + mbcnt64(ma);
                    CmpN[wv][pr][0][rank] = nj;
                    CmpW[wv][pr][0][rank] = eAr[j];
                }
                if ((mb >> l) & 1ull) {
                    int rank = baseB + mbcnt64(mb);
                    CmpN[wv][pr][1][rank] = nj;
                    CmpW[wv][pr][1][rank] = eBr[j];
                }
                baseA += __popcll(ma); baseB += __popcll(mb);
            }
        }
        asm volatile("s_waitcnt lgkmcnt(0)" ::: "memory");

        // fixed 16-iter gather: independent V-row loads, full ILP
        float od = 0.f, od2 = 0.f;
        #pragma unroll
        for (int k = 0; k < 16; ++k) {
            int nn  = CmpN[wv][pr][halfw][k];
            float w = CmpW[wv][pr][halfw][k];
            const float* vr = Vbh + (size_t)nn * 36;
            od = fmaf(w, vr[dpv], od);
            if (dpv < 4) od2 = fmaf(w, vr[32 + dpv], od2);
        }

        float invs = 1.0f / (halfw ? sumB : sumA);
        int t = ta + halfw;
        _Float16* orow = att16 + ((size_t)b * 1536 + t) * 288 + h * 36;
        orow[dpv] = (_Float16)(od * invs);
        if (dpv < 4) orow[32 + dpv] = (_Float16)(od2 * invs);
    }
}

// ---------------------------------------------------------------------------
extern "C" void kernel_launch(void* const* d_in, const int* in_sizes, int n_in,
                              void* d_out, int out_size, void* d_ws, size_t ws_size,
                              hipStream_t stream)
{
    (void)in_sizes; (void)n_in; (void)out_size; (void)ws_size;
    const float* x1      = (const float*)d_in[0];
    const float* x2      = (const float*)d_in[1];
    const float* x3      = (const float*)d_in[2];
    const float* xf      = (const float*)d_in[3];
    const float* emb     = (const float*)d_in[4];
    const float* un      = (const float*)d_in[5];
    const float* adaln_w = (const float*)d_in[6];
    const float* adaln_b = (const float*)d_in[7];
    const float* xfn_w   = (const float*)d_in[8];
    const float* xfn_b   = (const float*)d_in[9];
    const float* q_w     = (const float*)d_in[10];
    const float* q_b     = (const float*)d_in[11];
    const float* k_w     = (const float*)d_in[12];
    const float* k_b     = (const float*)d_in[13];
    const float* v_w     = (const float*)d_in[14];
    const float* v_b     = (const float*)d_in[15];
    const float* out_w   = (const float*)d_in[16];
    const float* out_b   = (const float*)d_in[17];
    float* out = (float*)d_out;

    float* ws = (float*)d_ws;
    float* eo = ws;                          // 16,384 f32
    float* Qb = eo + 16384;                  // 1,769,472 f32
    float* Kt = Qb + 1769472;                // 589,824 f32  [bh][36][512]
    float* Vb = Kt + 589824;                 // 589,824 f32  [bh][512][36]
    _Float16* xnqh = (_Float16*)(Vb + 589824);   // 3,145,728 h
    _Float16* xnql = xnqh + 3145728;
    _Float16* xfnh = xnql + 3145728;         // 8,388,608 h
    _Float16* xfnl = xfnh + 8388608;
    _Float16* att16 = xfnl + 8388608;        // 1,769,472 h
    _Float16* qwh  = att16 + 1769472;        // 442,368 h
    _Float16* qwl  = qwh + 442368;
    _Float16* kwh  = qwl + 442368;           // 147,456 h
    _Float16* kwl  = kwh + 147456;
    _Float16* vw16 = kwl + 147456;           // 147,456 h
    _Float16* ow16 = vw16 + 147456;          // 442,368 h

    prep_kernel<<<8704, 256, 0, stream>>>(q_w, k_w, v_w, out_w, emb,
                                          adaln_w, adaln_b, xfn_w, xfn_b,
                                          qwh, qwl, kwh, kwl, vw16, ow16, eo);
    ln_kernel<<<22528, 256, 0, stream>>>(x1, x2, x3, xf, eo, xnqh, xnql, xfnh, xfnl);
    gemm16_kernel<3, 0><<<288, 256, 0, stream>>>(xnqh, xnql, qwh, qwl, q_b, Qb);
    gemm16_kernel<3, 1><<<128, 256, 0, stream>>>(xfnh, xfnl, kwh, kwl, k_b, Kt);
    gemm16_kernel<3, 2><<<128, 256, 0, stream>>>(xfnh, nullptr, vw16, nullptr, v_b, Vb);
    attn_kernel<<<1536, 512, 0, stream>>>(Qb, Kt, Vb, un, att16);
    gemm16_kernel<4, 3><<<384, 256, 0, stream>>>(att16, nullptr, ow16, nullptr, out_b, out);
}